// Round 2
// baseline (1405.359 us; speedup 1.0000x reference)
//
#include <hip/hip_runtime.h>
#include <math.h>

typedef unsigned short u16;
typedef unsigned int   u32;

#define SS_    4
#define NH     4
#define Dh     32
#define Cdim   128
#define Ntok   64
#define WTOT   2048
#define Mrows  131072   // WTOT * Ntok
#define HIDDEN 512

__device__ __forceinline__ float bf2f(u16 u){
    union {u32 i; float f;} v; v.i = ((u32)u) << 16; return v.f;
}
__device__ __forceinline__ u16 f2bf(float f){
    union {float f; u32 i;} v; v.f = f;
    u32 x = v.i;
    return (u16)((x + 0x7fffu + ((x >> 16) & 1u)) >> 16);
}
__device__ __forceinline__ void unpack8(uint4 u, float* f){
    u32 w0=u.x, w1=u.y, w2=u.z, w3=u.w;
    f[0]=bf2f((u16)(w0&0xffffu)); f[1]=bf2f((u16)(w0>>16));
    f[2]=bf2f((u16)(w1&0xffffu)); f[3]=bf2f((u16)(w1>>16));
    f[4]=bf2f((u16)(w2&0xffffu)); f[5]=bf2f((u16)(w2>>16));
    f[6]=bf2f((u16)(w3&0xffffu)); f[7]=bf2f((u16)(w3>>16));
}

// token (windowed row) -> original token index (bijection, shift +4 both dims)
__device__ __forceinline__ int map_row_to_token(int r){
    int w = r >> 6, n = r & 63;
    int b = w >> 8, win = w & 255;
    int wy = win >> 4, wx = win & 15;
    int iy = n >> 3, ix = n & 7;
    int ro = (wy*8 + iy + SS_) & 127;
    int co = (wx*8 + ix + SS_) & 127;
    return (b << 14) + (ro << 7) + co;
}

// ---------------- fp32 -> bf16 weight conversion ----------------
__global__ void __launch_bounds__(256) cvt_kernel(const float* __restrict__ src,
        u16* __restrict__ dst, int n)
{
    int i = blockIdx.x * 256 + threadIdx.x;
    if (i < n) dst[i] = f2bf(src[i]);
}

// ---------------- LayerNorm (fp32 in, bf16 out) ----------------
// MODE 1: output row t is windowed/shifted: reads token map(t)
// MODE 0: straight token layout
template<int MODE>
__global__ void __launch_bounds__(128) ln_kernel(const float* __restrict__ xin,
        const float* __restrict__ g, const float* __restrict__ bsh,
        u16* __restrict__ outp)
{
    int t = blockIdx.x;
    int c = threadIdx.x;
    int src = (MODE == 1) ? map_row_to_token(t) : t;
    float val = xin[src*Cdim + c];
    float s = val, s2 = val*val;
    #pragma unroll
    for (int off = 32; off >= 1; off >>= 1){
        s  += __shfl_xor(s,  off, 64);
        s2 += __shfl_xor(s2, off, 64);
    }
    __shared__ float red[4];
    int wv = threadIdx.x >> 6;
    if ((threadIdx.x & 63) == 0){ red[wv*2] = s; red[wv*2+1] = s2; }
    __syncthreads();
    float ts = red[0] + red[2], ts2 = red[1] + red[3];
    float mean = ts * (1.0f/128.0f);
    float var  = ts2 * (1.0f/128.0f) - mean*mean;
    float inv  = rsqrtf(var + 1e-5f);
    float y = (val - mean) * inv * g[c] + bsh[c];
    outp[t*Cdim + c] = f2bf(y);
}

// ---------------- Generic GEMM: C[M,N] = A[M,K] @ Bw[N,K]^T + bias ----------------
// A, Bw are bf16 (internal); bias fp32.
// MODE 0: qkv scatter (o0=q scaled, o1=k, o2=v per-head layout, bf16)
// MODE 1: plain bf16 row-major out (o0, stride N)
// MODE 2: GELU(exact) bf16 out (o0, stride N)
// MODE 3: out = resid(fp32) + val, FP32 out (o0, stride N)
#define BM 64
#define BN 64
#define BK 32

template<int K, int N, int MODE>
__global__ void __launch_bounds__(256) gemm_kernel(
        const u16* __restrict__ A, const u16* __restrict__ Bw,
        const float* __restrict__ bias,
        void* __restrict__ o0, u16* __restrict__ o1, u16* __restrict__ o2,
        const float* __restrict__ resid)
{
    __shared__ float As[BM*33];
    __shared__ float Bs[BN*33];
    int t = threadIdx.x;
    int rowbase = blockIdx.x * BM;
    int nbase   = blockIdx.y * BN;
    int lrow = t >> 2;          // 0..63
    int lcol = (t & 3) * 8;     // 0,8,16,24
    int rowb = (t >> 4) * 4;
    int colb = (t & 15) * 4;
    float acc[4][4] = {};

    for (int kt = 0; kt < K; kt += BK){
        uint4 ua = *reinterpret_cast<const uint4*>(&A [(rowbase+lrow)*K + kt + lcol]);
        uint4 ub = *reinterpret_cast<const uint4*>(&Bw[(nbase  +lrow)*K + kt + lcol]);
        float af[8], bf[8];
        unpack8(ua, af); unpack8(ub, bf);
        #pragma unroll
        for (int i = 0; i < 8; i++){
            As[lrow*33 + lcol + i] = af[i];
            Bs[lrow*33 + lcol + i] = bf[i];
        }
        __syncthreads();
        #pragma unroll
        for (int kk = 0; kk < BK; kk++){
            float a0 = As[(rowb+0)*33+kk], a1 = As[(rowb+1)*33+kk];
            float a2 = As[(rowb+2)*33+kk], a3 = As[(rowb+3)*33+kk];
            float b0 = Bs[(colb+0)*33+kk], b1 = Bs[(colb+1)*33+kk];
            float b2 = Bs[(colb+2)*33+kk], b3 = Bs[(colb+3)*33+kk];
            acc[0][0] += a0*b0; acc[0][1] += a0*b1; acc[0][2] += a0*b2; acc[0][3] += a0*b3;
            acc[1][0] += a1*b0; acc[1][1] += a1*b1; acc[1][2] += a1*b2; acc[1][3] += a1*b3;
            acc[2][0] += a2*b0; acc[2][1] += a2*b1; acc[2][2] += a2*b2; acc[2][3] += a2*b3;
            acc[3][0] += a3*b0; acc[3][1] += a3*b1; acc[3][2] += a3*b2; acc[3][3] += a3*b3;
        }
        __syncthreads();
    }

    #pragma unroll
    for (int i = 0; i < 4; i++){
        int r = rowbase + rowb + i;
        #pragma unroll
        for (int j = 0; j < 4; j++){
            int c = nbase + colb + j;
            float v = acc[i][j] + bias[c];
            if (MODE == 0){
                int which = c >> 7;          // 0=q 1=k 2=v
                int h = (c >> 5) & 3;
                int d = c & 31;
                if (which == 0) v *= 0.17677669529663687f;  // 1/sqrt(32)
                u16* dst = (which == 0) ? (u16*)o0 : (which == 1) ? o1 : o2;
                int w = r >> 6, n = r & 63;
                dst[((w*NH + h)*Ntok + n)*Dh + d] = f2bf(v);
            } else if (MODE == 1){
                ((u16*)o0)[r*N + c] = f2bf(v);
            } else if (MODE == 2){
                float gl = 0.5f * v * (1.0f + erff(v * 0.70710678118654752f));
                ((u16*)o0)[r*N + c] = f2bf(gl);
            } else {
                ((float*)o0)[r*N + c] = resid[r*N + c] + v;
            }
        }
    }
}

// ---------------- Attention per (window, head) ----------------
__device__ __forceinline__ int reg_of(int coord){
    return coord < 120 ? 0 : (coord < 124 ? 1 : 2);
}

__global__ void __launch_bounds__(256) attn_kernel(
        const u16* __restrict__ qb, const u16* __restrict__ kb,
        const u16* __restrict__ vb, const float* __restrict__ rpb,
        u16* __restrict__ attno)
{
    __shared__ float qs[64*33], ks[64*33], vs[64*33];
    __shared__ float Sm[64*65];
    int blk = blockIdx.x;               // w*NH + h
    int h = blk & 3, w = blk >> 2;
    int win = w & 255;
    int wy = win >> 4, wx = win & 15;
    int t = threadIdx.x;

    // stage q/k/v: 64x32 each, 8 bf16 per thread
    {
        int n0 = t >> 2, d0 = (t & 3) * 8;
        const u16* qg = qb + blk*2048;
        const u16* kg = kb + blk*2048;
        const u16* vg = vb + blk*2048;
        float f[8];
        unpack8(*reinterpret_cast<const uint4*>(qg + t*8), f);
        #pragma unroll
        for (int i = 0; i < 8; i++) qs[n0*33 + d0 + i] = f[i];
        unpack8(*reinterpret_cast<const uint4*>(kg + t*8), f);
        #pragma unroll
        for (int i = 0; i < 8; i++) ks[n0*33 + d0 + i] = f[i];
        unpack8(*reinterpret_cast<const uint4*>(vg + t*8), f);
        #pragma unroll
        for (int i = 0; i < 8; i++) vs[n0*33 + d0 + i] = f[i];
    }
    __syncthreads();

    int r  = t >> 2;
    int mb = (t & 3) * 16;
    float qr[32];
    #pragma unroll
    for (int kk = 0; kk < 32; kk++) qr[kk] = qs[r*33 + kk];

    int iy = r >> 3, ix = r & 7;
    int regr = reg_of(wy*8 + iy)*3 + reg_of(wx*8 + ix);

    float sv[16];
    #pragma unroll
    for (int m = 0; m < 16; m++){
        int mm = mb + m;
        float s = 0.0f;
        #pragma unroll
        for (int kk = 0; kk < 32; kk++) s += qr[kk] * ks[mm*33 + kk];
        int jy = mm >> 3, jx = mm & 7;
        int bidx = (iy - jy + 7)*15 + (ix - jx + 7);
        s += rpb[bidx*NH + h];
        int regm = reg_of(wy*8 + jy)*3 + reg_of(wx*8 + jx);
        if (regm != regr) s -= 100.0f;
        sv[m] = s;
    }
    // softmax over the 64-wide row, spread across 4 adjacent lanes
    float mx = sv[0];
    #pragma unroll
    for (int m = 1; m < 16; m++) mx = fmaxf(mx, sv[m]);
    mx = fmaxf(mx, __shfl_xor(mx, 1, 64));
    mx = fmaxf(mx, __shfl_xor(mx, 2, 64));
    float sum = 0.0f;
    #pragma unroll
    for (int m = 0; m < 16; m++){ sv[m] = __expf(sv[m] - mx); sum += sv[m]; }
    sum += __shfl_xor(sum, 1, 64);
    sum += __shfl_xor(sum, 2, 64);
    float rinv = 1.0f / sum;
    #pragma unroll
    for (int m = 0; m < 16; m++) Sm[r*65 + mb + m] = sv[m] * rinv;
    __syncthreads();

    // O = P @ V : each thread does row r, 8 d-cols
    int db = (t & 3) * 8;
    float o[8] = {};
    for (int m = 0; m < 64; m++){
        float p = Sm[r*65 + m];
        #pragma unroll
        for (int j = 0; j < 8; j++) o[j] += p * vs[m*33 + db + j];
    }
    #pragma unroll
    for (int j = 0; j < 8; j++)
        attno[(w*64 + r)*Cdim + h*Dh + db + j] = f2bf(o[j]);
}

// ---------------- window-reverse + unshift + residual ----------------
__global__ void __launch_bounds__(256) scatter_res_kernel(
        const float* __restrict__ x, const u16* __restrict__ projout,
        float* __restrict__ x2)
{
    int gid = blockIdx.x * 256 + threadIdx.x;
    int r = gid >> 7, c = gid & 127;
    int dst = map_row_to_token(r);
    x2[dst*Cdim + c] = x[dst*Cdim + c] + bf2f(projout[gid]);
}

extern "C" void kernel_launch(void* const* d_in, const int* in_sizes, int n_in,
                              void* d_out, int out_size, void* d_ws, size_t ws_size,
                              hipStream_t stream) {
    const float* x     = (const float*)d_in[0];
    const float* rpb   = (const float*)d_in[1];
    const float* n1g   = (const float*)d_in[2];
    const float* n1b   = (const float*)d_in[3];
    const float* qkvw  = (const float*)d_in[4];
    const float* qkvb  = (const float*)d_in[5];
    const float* projw = (const float*)d_in[6];
    const float* projb = (const float*)d_in[7];
    const float* n2g   = (const float*)d_in[8];
    const float* n2b   = (const float*)d_in[9];
    const float* fc1w  = (const float*)d_in[10];
    const float* fc1b  = (const float*)d_in[11];
    const float* fc2w  = (const float*)d_in[12];
    const float* fc2b  = (const float*)d_in[13];
    float* out = (float*)d_out;

    if (ws_size < (size_t)235u * 1024u * 1024u) return;  // need ~225 MiB

    char* ws = (char*)d_ws;
    u16*  bufA  = (u16*)(ws);                         // 32 MiB: hwin -> projout -> h2
    u16*  qbuf  = (u16*)(ws + ((size_t)32  << 20));   // 32 MiB
    u16*  kbuf  = (u16*)(ws + ((size_t)64  << 20));   // 32 MiB
    u16*  vbuf  = (u16*)(ws + ((size_t)96  << 20));   // 32 MiB
    u16*  attno = (u16*)(ws + ((size_t)128 << 20));   // 32 MiB
    u16*  hid   = (u16*)(ws + ((size_t)32  << 20));   // 128 MiB (reuses q/k/v/attno)
    float* x2   = (float*)(ws + ((size_t)160 << 20)); // 64 MiB
    u16*  wb    = (u16*)(ws + ((size_t)224 << 20));   // 384 KiB bf16 weights
    u16*  qkvw_b = wb;                 // 49152
    u16*  projw_b = wb + 49152;        // 16384
    u16*  fc1w_b  = wb + 65536;        // 65536
    u16*  fc2w_b  = wb + 131072;       // 65536

    // 0. convert weights fp32 -> bf16
    cvt_kernel<<<(49152+255)/256, 256, 0, stream>>>(qkvw, qkvw_b, 49152);
    cvt_kernel<<<(16384+255)/256, 256, 0, stream>>>(projw, projw_b, 16384);
    cvt_kernel<<<(65536+255)/256, 256, 0, stream>>>(fc1w, fc1w_b, 65536);
    cvt_kernel<<<(65536+255)/256, 256, 0, stream>>>(fc2w, fc2w_b, 65536);

    // 1. LN1 + shift + window partition
    ln_kernel<1><<<Mrows, 128, 0, stream>>>(x, n1g, n1b, bufA);
    // 2. QKV GEMM
    gemm_kernel<128, 384, 0><<<dim3(Mrows/64, 6), 256, 0, stream>>>(
        bufA, qkvw_b, qkvb, qbuf, kbuf, vbuf, nullptr);
    // 3. windowed attention
    attn_kernel<<<WTOT*NH, 256, 0, stream>>>(qbuf, kbuf, vbuf, rpb, attno);
    // 4. proj GEMM
    gemm_kernel<128, 128, 1><<<dim3(Mrows/64, 2), 256, 0, stream>>>(
        attno, projw_b, projb, bufA, nullptr, nullptr, nullptr);
    // 5. window reverse + unshift + residual (fp32)
    scatter_res_kernel<<<(Mrows*Cdim)/256, 256, 0, stream>>>(x, bufA, x2);
    // 6. LN2
    ln_kernel<0><<<Mrows, 128, 0, stream>>>(x2, n2g, n2b, bufA);
    // 7. FC1 + GELU
    gemm_kernel<128, 512, 2><<<dim3(Mrows/64, 8), 256, 0, stream>>>(
        bufA, fc1w_b, fc1b, hid, nullptr, nullptr, nullptr);
    // 8. FC2 + residual -> out (fp32)
    gemm_kernel<512, 128, 3><<<dim3(Mrows/64, 2), 256, 0, stream>>>(
        hid, fc2w_b, fc2b, out, nullptr, nullptr, x2);
}

// Round 4
// 628.403 us; speedup vs baseline: 2.2364x; 2.2364x over previous
//
#include <hip/hip_runtime.h>
#include <math.h>

typedef unsigned short u16;
typedef unsigned int   u32;

#define SS_    4
#define NH     4
#define Dh     32
#define Cdim   128
#define Ntok   64
#define WTOT   2048
#define Mrows  131072   // WTOT * Ntok
#define HIDDEN 512
#define STR    40       // padded LDS row stride (u16): 80 B -> 2-way banks (free)

typedef __bf16 bf16x8 __attribute__((ext_vector_type(8)));
typedef float  f32x4  __attribute__((ext_vector_type(4)));

__device__ __forceinline__ float bf2f(u16 u){
    union {u32 i; float f;} v; v.i = ((u32)u) << 16; return v.f;
}
__device__ __forceinline__ u16 f2bf(float f){
    union {float f; u32 i;} v; v.f = f;
    u32 x = v.i;
    return (u16)((x + 0x7fffu + ((x >> 16) & 1u)) >> 16);
}
__device__ __forceinline__ void unpack8(uint4 u, float* f){
    u32 w0=u.x, w1=u.y, w2=u.z, w3=u.w;
    f[0]=bf2f((u16)(w0&0xffffu)); f[1]=bf2f((u16)(w0>>16));
    f[2]=bf2f((u16)(w1&0xffffu)); f[3]=bf2f((u16)(w1>>16));
    f[4]=bf2f((u16)(w2&0xffffu)); f[5]=bf2f((u16)(w2>>16));
    f[6]=bf2f((u16)(w3&0xffffu)); f[7]=bf2f((u16)(w3>>16));
}

// token (windowed row) -> original token index (bijection, shift +4 both dims)
__device__ __forceinline__ int map_row_to_token(int r){
    int w = r >> 6, n = r & 63;
    int b = w >> 8, win = w & 255;
    int wy = win >> 4, wx = win & 15;
    int iy = n >> 3, ix = n & 7;
    int ro = (wy*8 + iy + SS_) & 127;
    int co = (wx*8 + ix + SS_) & 127;
    return (b << 14) + (ro << 7) + co;
}

// ---------------- fp32 -> bf16 weight conversion ----------------
__global__ void __launch_bounds__(256) cvt_kernel(const float* __restrict__ src,
        u16* __restrict__ dst, int n)
{
    int i = blockIdx.x * 256 + threadIdx.x;
    if (i < n) dst[i] = f2bf(src[i]);
}

// ---------------- LayerNorm (fp32 in, bf16 out) ----------------
template<int MODE>
__global__ void __launch_bounds__(128) ln_kernel(const float* __restrict__ xin,
        const float* __restrict__ g, const float* __restrict__ bsh,
        u16* __restrict__ outp)
{
    int t = blockIdx.x;
    int c = threadIdx.x;
    int src = (MODE == 1) ? map_row_to_token(t) : t;
    float val = xin[src*Cdim + c];
    float s = val, s2 = val*val;
    #pragma unroll
    for (int off = 32; off >= 1; off >>= 1){
        s  += __shfl_xor(s,  off, 64);
        s2 += __shfl_xor(s2, off, 64);
    }
    __shared__ float red[4];
    int wv = threadIdx.x >> 6;
    if ((threadIdx.x & 63) == 0){ red[wv*2] = s; red[wv*2+1] = s2; }
    __syncthreads();
    float ts = red[0] + red[2], ts2 = red[1] + red[3];
    float mean = ts * (1.0f/128.0f);
    float var  = ts2 * (1.0f/128.0f) - mean*mean;
    float inv  = rsqrtf(var + 1e-5f);
    float y = (val - mean) * inv * g[c] + bsh[c];
    outp[t*Cdim + c] = f2bf(y);
}

// ---------------- MFMA GEMM: C[M,N] = A[M,K] @ Bw[N,K]^T + bias ----------------
// 128x128 tile, 4 waves in 2x2, each wave 64x64 = 4x4 mfma_f32_16x16x32_bf16.
// Staging: uint4 global loads -> registers -> ds_write_b128 (padded stride 40).
// MODE 0: qkv scatter; 1: plain bf16; 2: GELU bf16; 3: resid(fp32)+v -> fp32
template<int K, int N, int MODE>
__global__ void __launch_bounds__(256) gemm_kernel(
        const u16* __restrict__ A, const u16* __restrict__ Bw,
        const float* __restrict__ bias,
        void* __restrict__ o0, u16* __restrict__ o1, u16* __restrict__ o2,
        const float* __restrict__ resid)
{
    __shared__ __align__(16) u16 As[128*STR];
    __shared__ __align__(16) u16 Bs[128*STR];
    int t = threadIdx.x;
    int wave = t >> 6, lane = t & 63;
    int rowbase = blockIdx.x * 128;
    int nbase   = blockIdx.y * 128;
    int wr = wave & 1, wc = wave >> 1;
    int m = lane & 15, quad = lane >> 4;

    int lrow = t >> 2;          // 0..63
    int lk   = (t & 3) * 8;     // 0,8,16,24

    f32x4 acc[4][4] = {};

    for (int kt = 0; kt < K; kt += 32){
        uint4 a0 = *reinterpret_cast<const uint4*>(&A [(size_t)(rowbase + lrow     )*K + kt + lk]);
        uint4 a1 = *reinterpret_cast<const uint4*>(&A [(size_t)(rowbase + lrow + 64)*K + kt + lk]);
        uint4 b0 = *reinterpret_cast<const uint4*>(&Bw[(size_t)(nbase   + lrow     )*K + kt + lk]);
        uint4 b1 = *reinterpret_cast<const uint4*>(&Bw[(size_t)(nbase   + lrow + 64)*K + kt + lk]);
        __syncthreads();   // previous iteration's LDS reads complete
        *reinterpret_cast<uint4*>(&As[ lrow      *STR + lk]) = a0;
        *reinterpret_cast<uint4*>(&As[(lrow + 64)*STR + lk]) = a1;
        *reinterpret_cast<uint4*>(&Bs[ lrow      *STR + lk]) = b0;
        *reinterpret_cast<uint4*>(&Bs[(lrow + 64)*STR + lk]) = b1;
        __syncthreads();

        bf16x8 afr[4], bfr[4];
        #pragma unroll
        for (int i = 0; i < 4; i++){
            afr[i] = *(const bf16x8*)&As[(wr*64 + i*16 + m)*STR + quad*8];
            bfr[i] = *(const bf16x8*)&Bs[(wc*64 + i*16 + m)*STR + quad*8];
        }
        #pragma unroll
        for (int i = 0; i < 4; i++)
            #pragma unroll
            for (int j = 0; j < 4; j++)
                acc[i][j] = __builtin_amdgcn_mfma_f32_16x16x32_bf16(
                                afr[i], bfr[j], acc[i][j], 0, 0, 0);
    }

    #pragma unroll
    for (int i = 0; i < 4; i++){
        #pragma unroll
        for (int j = 0; j < 4; j++){
            int c = nbase + wc*64 + j*16 + m;
            float bia = bias[c];
            #pragma unroll
            for (int rg = 0; rg < 4; rg++){
                int r = rowbase + wr*64 + i*16 + quad*4 + rg;
                float v = acc[i][j][rg] + bia;
                if (MODE == 0){
                    int which = c >> 7;          // 0=q 1=k 2=v
                    int h = (c >> 5) & 3;
                    int d = c & 31;
                    if (which == 0) v *= 0.17677669529663687f;  // 1/sqrt(32)
                    u16* dst = (which == 0) ? (u16*)o0 : (which == 1) ? o1 : o2;
                    int w = r >> 6, n = r & 63;
                    dst[((w*NH + h)*Ntok + n)*Dh + d] = f2bf(v);
                } else if (MODE == 1){
                    ((u16*)o0)[(size_t)r*N + c] = f2bf(v);
                } else if (MODE == 2){
                    float gl = 0.5f * v * (1.0f + erff(v * 0.70710678118654752f));
                    ((u16*)o0)[(size_t)r*N + c] = f2bf(gl);
                } else {
                    ((float*)o0)[(size_t)r*N + c] = resid[(size_t)r*N + c] + v;
                }
            }
        }
    }
}

// ---------------- Attention per (window, head) ----------------
__device__ __forceinline__ int reg_of(int coord){
    return coord < 120 ? 0 : (coord < 124 ? 1 : 2);
}

__global__ void __launch_bounds__(256) attn_kernel(
        const u16* __restrict__ qb, const u16* __restrict__ kb,
        const u16* __restrict__ vb, const float* __restrict__ rpb,
        u16* __restrict__ attno)
{
    __shared__ float qs[64*33], ks[64*33], vs[64*33];
    __shared__ float Sm[64*65];
    int blk = blockIdx.x;               // w*NH + h
    int h = blk & 3, w = blk >> 2;
    int win = w & 255;
    int wy = win >> 4, wx = win & 15;
    int t = threadIdx.x;

    {
        int n0 = t >> 2, d0 = (t & 3) * 8;
        const u16* qg = qb + blk*2048;
        const u16* kg = kb + blk*2048;
        const u16* vg = vb + blk*2048;
        float f[8];
        unpack8(*reinterpret_cast<const uint4*>(qg + t*8), f);
        #pragma unroll
        for (int i = 0; i < 8; i++) qs[n0*33 + d0 + i] = f[i];
        unpack8(*reinterpret_cast<const uint4*>(kg + t*8), f);
        #pragma unroll
        for (int i = 0; i < 8; i++) ks[n0*33 + d0 + i] = f[i];
        unpack8(*reinterpret_cast<const uint4*>(vg + t*8), f);
        #pragma unroll
        for (int i = 0; i < 8; i++) vs[n0*33 + d0 + i] = f[i];
    }
    __syncthreads();

    int r  = t >> 2;
    int mb = (t & 3) * 16;
    float qr[32];
    #pragma unroll
    for (int kk = 0; kk < 32; kk++) qr[kk] = qs[r*33 + kk];

    int iy = r >> 3, ix = r & 7;
    int regr = reg_of(wy*8 + iy)*3 + reg_of(wx*8 + ix);

    float sv[16];
    #pragma unroll
    for (int m = 0; m < 16; m++){
        int mm = mb + m;
        float s = 0.0f;
        #pragma unroll
        for (int kk = 0; kk < 32; kk++) s += qr[kk] * ks[mm*33 + kk];
        int jy = mm >> 3, jx = mm & 7;
        int bidx = (iy - jy + 7)*15 + (ix - jx + 7);
        s += rpb[bidx*NH + h];
        int regm = reg_of(wy*8 + jy)*3 + reg_of(wx*8 + jx);
        if (regm != regr) s -= 100.0f;
        sv[m] = s;
    }
    float mx = sv[0];
    #pragma unroll
    for (int m = 1; m < 16; m++) mx = fmaxf(mx, sv[m]);
    mx = fmaxf(mx, __shfl_xor(mx, 1, 64));
    mx = fmaxf(mx, __shfl_xor(mx, 2, 64));
    float sum = 0.0f;
    #pragma unroll
    for (int m = 0; m < 16; m++){ sv[m] = __expf(sv[m] - mx); sum += sv[m]; }
    sum += __shfl_xor(sum, 1, 64);
    sum += __shfl_xor(sum, 2, 64);
    float rinv = 1.0f / sum;
    #pragma unroll
    for (int m = 0; m < 16; m++) Sm[r*65 + mb + m] = sv[m] * rinv;
    __syncthreads();

    int db = (t & 3) * 8;
    float o[8] = {};
    for (int m = 0; m < 64; m++){
        float p = Sm[r*65 + m];
        #pragma unroll
        for (int j = 0; j < 8; j++) o[j] += p * vs[m*33 + db + j];
    }
    #pragma unroll
    for (int j = 0; j < 8; j++)
        attno[(w*64 + r)*Cdim + h*Dh + db + j] = f2bf(o[j]);
}

// ---------------- window-reverse + unshift + residual ----------------
__global__ void __launch_bounds__(256) scatter_res_kernel(
        const float* __restrict__ x, const u16* __restrict__ projout,
        float* __restrict__ x2)
{
    int gid = blockIdx.x * 256 + threadIdx.x;
    int r = gid >> 7, c = gid & 127;
    int dst = map_row_to_token(r);
    x2[dst*Cdim + c] = x[dst*Cdim + c] + bf2f(projout[gid]);
}

extern "C" void kernel_launch(void* const* d_in, const int* in_sizes, int n_in,
                              void* d_out, int out_size, void* d_ws, size_t ws_size,
                              hipStream_t stream) {
    const float* x     = (const float*)d_in[0];
    const float* rpb   = (const float*)d_in[1];
    const float* n1g   = (const float*)d_in[2];
    const float* n1b   = (const float*)d_in[3];
    const float* qkvw  = (const float*)d_in[4];
    const float* qkvb  = (const float*)d_in[5];
    const float* projw = (const float*)d_in[6];
    const float* projb = (const float*)d_in[7];
    const float* n2g   = (const float*)d_in[8];
    const float* n2b   = (const float*)d_in[9];
    const float* fc1w  = (const float*)d_in[10];
    const float* fc1b  = (const float*)d_in[11];
    const float* fc2w  = (const float*)d_in[12];
    const float* fc2b  = (const float*)d_in[13];
    float* out = (float*)d_out;

    if (ws_size < (size_t)235u * 1024u * 1024u) return;  // need ~225 MiB

    char* ws = (char*)d_ws;
    u16*  bufA  = (u16*)(ws);                         // 32 MiB: hwin -> projout -> h2
    u16*  qbuf  = (u16*)(ws + ((size_t)32  << 20));   // 32 MiB
    u16*  kbuf  = (u16*)(ws + ((size_t)64  << 20));   // 32 MiB
    u16*  vbuf  = (u16*)(ws + ((size_t)96  << 20));   // 32 MiB
    u16*  attno = (u16*)(ws + ((size_t)128 << 20));   // 32 MiB
    u16*  hid   = (u16*)(ws + ((size_t)32  << 20));   // 128 MiB (reuses q/k/v/attno)
    float* x2   = (float*)(ws + ((size_t)160 << 20)); // 64 MiB
    u16*  wb    = (u16*)(ws + ((size_t)224 << 20));   // 384 KiB bf16 weights
    u16*  qkvw_b = wb;                 // 49152
    u16*  projw_b = wb + 49152;        // 16384
    u16*  fc1w_b  = wb + 65536;        // 65536
    u16*  fc2w_b  = wb + 131072;       // 65536

    // 0. convert weights fp32 -> bf16
    cvt_kernel<<<(49152+255)/256, 256, 0, stream>>>(qkvw, qkvw_b, 49152);
    cvt_kernel<<<(16384+255)/256, 256, 0, stream>>>(projw, projw_b, 16384);
    cvt_kernel<<<(65536+255)/256, 256, 0, stream>>>(fc1w, fc1w_b, 65536);
    cvt_kernel<<<(65536+255)/256, 256, 0, stream>>>(fc2w, fc2w_b, 65536);

    // 1. LN1 + shift + window partition
    ln_kernel<1><<<Mrows, 128, 0, stream>>>(x, n1g, n1b, bufA);
    // 2. QKV GEMM (MFMA)
    gemm_kernel<128, 384, 0><<<dim3(Mrows/128, 3), 256, 0, stream>>>(
        bufA, qkvw_b, qkvb, qbuf, kbuf, vbuf, nullptr);
    // 3. windowed attention
    attn_kernel<<<WTOT*NH, 256, 0, stream>>>(qbuf, kbuf, vbuf, rpb, attno);
    // 4. proj GEMM (MFMA)
    gemm_kernel<128, 128, 1><<<dim3(Mrows/128, 1), 256, 0, stream>>>(
        attno, projw_b, projb, bufA, nullptr, nullptr, nullptr);
    // 5. window reverse + unshift + residual (fp32)
    scatter_res_kernel<<<(Mrows*Cdim)/256, 256, 0, stream>>>(x, bufA, x2);
    // 6. LN2
    ln_kernel<0><<<Mrows, 128, 0, stream>>>(x2, n2g, n2b, bufA);
    // 7. FC1 + GELU (MFMA)
    gemm_kernel<128, 512, 2><<<dim3(Mrows/128, 4), 256, 0, stream>>>(
        bufA, fc1w_b, fc1b, hid, nullptr, nullptr, nullptr);
    // 8. FC2 + residual -> out (fp32, MFMA)
    gemm_kernel<512, 128, 3><<<dim3(Mrows/128, 1), 256, 0, stream>>>(
        hid, fc2w_b, fc2b, out, nullptr, nullptr, x2);
}

// Round 6
// 549.290 us; speedup vs baseline: 2.5585x; 1.1440x over previous
//
#include <hip/hip_runtime.h>
#include <math.h>

typedef unsigned short u16;
typedef unsigned int   u32;

#define SS_    4
#define NH     4
#define Dh     32
#define Cdim   128
#define Ntok   64
#define WTOT   2048
#define Mrows  131072   // WTOT * Ntok
#define HIDDEN 512
#define PSTR   72       // P LDS row stride (u16): 144 B, 16-B aligned, low-conflict

typedef __bf16 bf16x8 __attribute__((ext_vector_type(8)));
typedef float  f32x4  __attribute__((ext_vector_type(4)));

__device__ __forceinline__ float bf2f(u16 u){
    union {u32 i; float f;} v; v.i = ((u32)u) << 16; return v.f;
}
__device__ __forceinline__ u16 f2bf(float f){
    union {float f; u32 i;} v; v.f = f;
    u32 x = v.i;
    return (u16)((x + 0x7fffu + ((x >> 16) & 1u)) >> 16);
}

// token (windowed row) -> original token index (bijection, shift +4 both dims)
__device__ __forceinline__ int map_row_to_token(int r){
    int w = r >> 6, n = r & 63;
    int b = w >> 8, win = w & 255;
    int wy = win >> 4, wx = win & 15;
    int iy = n >> 3, ix = n & 7;
    int ro = (wy*8 + iy + SS_) & 127;
    int co = (wx*8 + ix + SS_) & 127;
    return (b << 14) + (ro << 7) + co;
}

// ---------------- fp32 -> bf16 weight conversion ----------------
__global__ void __launch_bounds__(256) cvt_kernel(const float* __restrict__ src,
        u16* __restrict__ dst, int n)
{
    int i = blockIdx.x * 256 + threadIdx.x;
    if (i < n) dst[i] = f2bf(src[i]);
}

// ---------------- bias+mask table: bm[cls][h][row][col], 4*4*64*64 fp32 ----------
__global__ void __launch_bounds__(256) bm_kernel(const float* __restrict__ rpb,
        float* __restrict__ bmt)
{
    int e = blockIdx.x * 256 + threadIdx.x;     // 65536 total
    int cls = e >> 14, h = (e >> 12) & 3, row = (e >> 6) & 63, col = e & 63;
    int iy = row >> 3, ix = row & 7, jy = col >> 3, jx = col & 7;
    int bidx = (iy - jy + 7)*15 + (ix - jx + 7);
    float bias = rpb[bidx*NH + h];
    int ybit = cls >> 1, xbit = cls & 1;
    int ri = (ybit ? (iy < 4 ? 1 : 2) : 0)*3 + (xbit ? (ix < 4 ? 1 : 2) : 0);
    int rj = (ybit ? (jy < 4 ? 1 : 2) : 0)*3 + (xbit ? (jx < 4 ? 1 : 2) : 0);
    bmt[e] = bias + ((ri != rj) ? -100.0f : 0.0f);
}

// ---------------- LayerNorm 1 (fp32 in, bf16 windowed out) ----------------
__global__ void __launch_bounds__(128) ln1_kernel(const float* __restrict__ xin,
        const float* __restrict__ g, const float* __restrict__ bsh,
        u16* __restrict__ outp)
{
    int t = blockIdx.x;
    int c = threadIdx.x;
    int src = map_row_to_token(t);
    float val = xin[(size_t)src*Cdim + c];
    float s = val, s2 = val*val;
    #pragma unroll
    for (int off = 32; off >= 1; off >>= 1){
        s  += __shfl_xor(s,  off, 64);
        s2 += __shfl_xor(s2, off, 64);
    }
    __shared__ float red[4];
    int wv = threadIdx.x >> 6;
    if ((threadIdx.x & 63) == 0){ red[wv*2] = s; red[wv*2+1] = s2; }
    __syncthreads();
    float ts = red[0] + red[2], ts2 = red[1] + red[3];
    float mean = ts * (1.0f/128.0f);
    float var  = ts2 * (1.0f/128.0f) - mean*mean;
    float inv  = rsqrtf(var + 1e-5f);
    outp[(size_t)t*Cdim + c] = f2bf((val - mean) * inv * g[c] + bsh[c]);
}

// ------- fused: window-reverse + unshift + residual -> x2 (fp32), then LN2 -> bf16
// NOTE: projout, x2, ln2out are pairwise-DISJOINT buffers (round-5 race fix).
__global__ void __launch_bounds__(128) resln_kernel(const float* __restrict__ x,
        const u16* __restrict__ projout,
        const float* __restrict__ g, const float* __restrict__ bsh,
        float* __restrict__ x2, u16* __restrict__ outp)
{
    int t = blockIdx.x;      // token index
    int c = threadIdx.x;
    int b = t >> 14, ro = (t >> 7) & 127, co = t & 127;
    int y  = (ro + 128 - SS_) & 127;
    int xq = (co + 128 - SS_) & 127;
    int r = (((b << 8) | ((y >> 3) << 4) | (xq >> 3)) << 6) + (y & 7)*8 + (xq & 7);
    float val = x[(size_t)t*Cdim + c] + bf2f(projout[(size_t)r*Cdim + c]);
    x2[(size_t)t*Cdim + c] = val;
    float s = val, s2 = val*val;
    #pragma unroll
    for (int off = 32; off >= 1; off >>= 1){
        s  += __shfl_xor(s,  off, 64);
        s2 += __shfl_xor(s2, off, 64);
    }
    __shared__ float red[4];
    int wv = threadIdx.x >> 6;
    if ((threadIdx.x & 63) == 0){ red[wv*2] = s; red[wv*2+1] = s2; }
    __syncthreads();
    float ts = red[0] + red[2], ts2 = red[1] + red[3];
    float mean = ts * (1.0f/128.0f);
    float var  = ts2 * (1.0f/128.0f) - mean*mean;
    float inv  = rsqrtf(var + 1e-5f);
    outp[(size_t)t*Cdim + c] = f2bf((val - mean) * inv * g[c] + bsh[c]);
}

// ---------------- Registers-only MFMA GEMM: C = A[M,K] @ Bw[N,K]^T + bias -------
// 128x128 tile, 4 waves 2x2 (each 64x64). No LDS, no barriers.
// MODE 0: qkv scatter (q scaled, k normal, v TRANSPOSED [w][h][d][n])
// MODE 1: plain bf16; MODE 2: GELU bf16; MODE 3: resid(fp32)+v -> fp32
template<int K, int N, int MODE>
__global__ void __launch_bounds__(256) gemm_kernel(
        const u16* __restrict__ A, const u16* __restrict__ Bw,
        const float* __restrict__ bias,
        void* __restrict__ o0, u16* __restrict__ o1, u16* __restrict__ o2,
        const float* __restrict__ resid)
{
    int t = threadIdx.x;
    int wave = t >> 6, lane = t & 63;
    int wr = wave & 1, wc = wave >> 1;
    int m = lane & 15, quad = lane >> 4;
    size_t rowbase = (size_t)blockIdx.x * 128 + wr*64;
    size_t nb      = (size_t)blockIdx.y * 128 + wc*64;

    f32x4 acc[4][4] = {};

    #pragma unroll 4
    for (int s = 0; s < K/32; s++){
        bf16x8 aq[4], bk[4];
        #pragma unroll
        for (int i = 0; i < 4; i++)
            aq[i] = *(const bf16x8*)&A[(rowbase + i*16 + m)*K + s*32 + quad*8];
        #pragma unroll
        for (int j = 0; j < 4; j++)
            bk[j] = *(const bf16x8*)&Bw[(nb + j*16 + m)*K + s*32 + quad*8];
        #pragma unroll
        for (int i = 0; i < 4; i++)
            #pragma unroll
            for (int j = 0; j < 4; j++)
                acc[i][j] = __builtin_amdgcn_mfma_f32_16x16x32_bf16(
                                aq[i], bk[j], acc[i][j], 0, 0, 0);
    }

    #pragma unroll
    for (int i = 0; i < 4; i++){
        #pragma unroll
        for (int j = 0; j < 4; j++){
            int c = (int)nb + j*16 + m;
            float bia = bias[c];
            #pragma unroll
            for (int rg = 0; rg < 4; rg++){
                int r = (int)rowbase + i*16 + quad*4 + rg;
                float v = acc[i][j][rg] + bia;
                if (MODE == 0){
                    int which = c >> 7;          // 0=q 1=k 2=v
                    int h = (c >> 5) & 3;
                    int d = c & 31;
                    int w = r >> 6, n = r & 63;
                    if (which == 0){
                        ((u16*)o0)[((size_t)(w*NH + h)*Ntok + n)*Dh + d] =
                            f2bf(v * 0.17677669529663687f);
                    } else if (which == 1){
                        o1[((size_t)(w*NH + h)*Ntok + n)*Dh + d] = f2bf(v);
                    } else {   // v transposed: [w][h][d][n]
                        o2[((size_t)(w*NH + h)*Dh + d)*Ntok + n] = f2bf(v);
                    }
                } else if (MODE == 1){
                    ((u16*)o0)[(size_t)r*N + c] = f2bf(v);
                } else if (MODE == 2){
                    float gl = 0.5f * v * (1.0f + erff(v * 0.70710678118654752f));
                    ((u16*)o0)[(size_t)r*N + c] = f2bf(gl);
                } else {
                    ((float*)o0)[(size_t)r*N + c] = resid[(size_t)r*N + c] + v;
                }
            }
        }
    }
}

// ---------------- MFMA attention: block = window, wave = head ----------------
__global__ void __launch_bounds__(256) attn_kernel(
        const u16* __restrict__ qb, const u16* __restrict__ kb,
        const u16* __restrict__ vt, const float* __restrict__ bmt,
        u16* __restrict__ attno)
{
    __shared__ __align__(16) u16 P[NH][64*PSTR];
    int w = blockIdx.x;
    int win = w & 255;
    int wy = win >> 4, wx = win & 15;
    int cls = ((wy == 15) ? 2 : 0) | ((wx == 15) ? 1 : 0);
    int t = threadIdx.x;
    int h = t >> 6, lane = t & 63;
    int m = lane & 15, quad = lane >> 4;

    const u16* qg = qb + (size_t)(w*NH + h)*2048;   // [n][d]
    const u16* kg = kb + (size_t)(w*NH + h)*2048;   // [n][d]
    const u16* vg = vt + (size_t)(w*NH + h)*2048;   // [d][n] (transposed)
    const float* bm = bmt + (size_t)(cls*NH + h)*4096;

    // S = Q @ K^T  (64x64, one K=32 step)
    bf16x8 aq[4], bk[4];
    #pragma unroll
    for (int i = 0; i < 4; i++)
        aq[i] = *(const bf16x8*)&qg[(i*16 + m)*32 + quad*8];
    #pragma unroll
    for (int j = 0; j < 4; j++)
        bk[j] = *(const bf16x8*)&kg[(j*16 + m)*32 + quad*8];
    f32x4 S[4][4] = {};
    #pragma unroll
    for (int i = 0; i < 4; i++)
        #pragma unroll
        for (int j = 0; j < 4; j++)
            S[i][j] = __builtin_amdgcn_mfma_f32_16x16x32_bf16(
                          aq[i], bk[j], S[i][j], 0, 0, 0);

    // bias+mask add, row softmax (row = i*16 + quad*4 + rg; cols across 16 lanes x 4 j)
    #pragma unroll
    for (int i = 0; i < 4; i++){
        #pragma unroll
        for (int rg = 0; rg < 4; rg++){
            int row = i*16 + quad*4 + rg;
            float s0 = S[i][0][rg] + bm[row*64 +  0 + m];
            float s1 = S[i][1][rg] + bm[row*64 + 16 + m];
            float s2 = S[i][2][rg] + bm[row*64 + 32 + m];
            float s3 = S[i][3][rg] + bm[row*64 + 48 + m];
            float mx = fmaxf(fmaxf(s0, s1), fmaxf(s2, s3));
            mx = fmaxf(mx, __shfl_xor(mx, 1, 64));
            mx = fmaxf(mx, __shfl_xor(mx, 2, 64));
            mx = fmaxf(mx, __shfl_xor(mx, 4, 64));
            mx = fmaxf(mx, __shfl_xor(mx, 8, 64));
            s0 = __expf(s0 - mx); s1 = __expf(s1 - mx);
            s2 = __expf(s2 - mx); s3 = __expf(s3 - mx);
            float sm = s0 + s1 + s2 + s3;
            sm += __shfl_xor(sm, 1, 64);
            sm += __shfl_xor(sm, 2, 64);
            sm += __shfl_xor(sm, 4, 64);
            sm += __shfl_xor(sm, 8, 64);
            float rinv = 1.0f / sm;
            u16* pr = &P[h][row*PSTR];
            pr[ 0 + m] = f2bf(s0 * rinv);
            pr[16 + m] = f2bf(s1 * rinv);
            pr[32 + m] = f2bf(s2 * rinv);
            pr[48 + m] = f2bf(s3 * rinv);
        }
    }
    // per-wave private P rows: same-wave LDS ordering suffices, no barrier

    // O = P @ V  (64x32, two K=32 steps)
    f32x4 O[4][2] = {};
    #pragma unroll
    for (int s2 = 0; s2 < 2; s2++){
        bf16x8 pa[4], bv[2];
        #pragma unroll
        for (int i = 0; i < 4; i++)
            pa[i] = *(const bf16x8*)&P[h][(i*16 + m)*PSTR + s2*32 + quad*8];
        #pragma unroll
        for (int dt = 0; dt < 2; dt++)
            bv[dt] = *(const bf16x8*)&vg[(dt*16 + m)*64 + s2*32 + quad*8];
        #pragma unroll
        for (int i = 0; i < 4; i++)
            #pragma unroll
            for (int dt = 0; dt < 2; dt++)
                O[i][dt] = __builtin_amdgcn_mfma_f32_16x16x32_bf16(
                               pa[i], bv[dt], O[i][dt], 0, 0, 0);
    }

    #pragma unroll
    for (int i = 0; i < 4; i++)
        #pragma unroll
        for (int dt = 0; dt < 2; dt++)
            #pragma unroll
            for (int rg = 0; rg < 4; rg++){
                int token = w*64 + i*16 + quad*4 + rg;
                attno[(size_t)token*Cdim + h*Dh + dt*16 + m] = f2bf(O[i][dt][rg]);
            }
}

extern "C" void kernel_launch(void* const* d_in, const int* in_sizes, int n_in,
                              void* d_out, int out_size, void* d_ws, size_t ws_size,
                              hipStream_t stream) {
    const float* x     = (const float*)d_in[0];
    const float* rpb   = (const float*)d_in[1];
    const float* n1g   = (const float*)d_in[2];
    const float* n1b   = (const float*)d_in[3];
    const float* qkvw  = (const float*)d_in[4];
    const float* qkvb  = (const float*)d_in[5];
    const float* projw = (const float*)d_in[6];
    const float* projb = (const float*)d_in[7];
    const float* n2g   = (const float*)d_in[8];
    const float* n2b   = (const float*)d_in[9];
    const float* fc1w  = (const float*)d_in[10];
    const float* fc1b  = (const float*)d_in[11];
    const float* fc2w  = (const float*)d_in[12];
    const float* fc2b  = (const float*)d_in[13];
    float* out = (float*)d_out;

    if (ws_size < (size_t)230u * 1024u * 1024u) return;

    // Disjoint-lifetime layout (race-free):
    //   region        offset   size   lifetime
    //   ln1out        0        32M    s1 -> s2
    //   projout       0        32M    s4 -> s5   (ln1out dead)
    //   hid           0        128M   s6 -> s7   (q/k/v/projout dead)
    //   qbuf          32M      32M    s2 -> s3
    //   kbuf          64M      32M    s2 -> s3
    //   vbuf          96M      32M    s2 -> s3
    //   attno         128M     32M    s3 -> s4
    //   x2            128M     64M    s5 -> s7   (attno dead)
    //   ln2out        192M     32M    s5 -> s6
    //   weights/bmt   224M     ~2M    s0 -> end
    char* ws = (char*)d_ws;
    u16*  ln1out  = (u16*)(ws);
    u16*  projout = (u16*)(ws);
    u16*  hid     = (u16*)(ws);
    u16*  qbuf    = (u16*)(ws + ((size_t)32  << 20));
    u16*  kbuf    = (u16*)(ws + ((size_t)64  << 20));
    u16*  vbuf    = (u16*)(ws + ((size_t)96  << 20));
    u16*  attno   = (u16*)(ws + ((size_t)128 << 20));
    float* x2     = (float*)(ws + ((size_t)128 << 20));
    u16*  ln2out  = (u16*)(ws + ((size_t)192 << 20));
    u16*  wb      = (u16*)(ws + ((size_t)224 << 20));
    u16*  qkvw_b  = wb;                // 49152
    u16*  projw_b = wb + 49152;        // 16384
    u16*  fc1w_b  = wb + 65536;        // 65536
    u16*  fc2w_b  = wb + 131072;       // 65536
    float* bmt    = (float*)(ws + ((size_t)225 << 20)); // 256 KiB

    // 0. weight conversions + bias/mask table
    cvt_kernel<<<(49152+255)/256, 256, 0, stream>>>(qkvw, qkvw_b, 49152);
    cvt_kernel<<<(16384+255)/256, 256, 0, stream>>>(projw, projw_b, 16384);
    cvt_kernel<<<(65536+255)/256, 256, 0, stream>>>(fc1w, fc1w_b, 65536);
    cvt_kernel<<<(65536+255)/256, 256, 0, stream>>>(fc2w, fc2w_b, 65536);
    bm_kernel<<<256, 256, 0, stream>>>(rpb, bmt);

    // 1. LN1 + shift + window partition
    ln1_kernel<<<Mrows, 128, 0, stream>>>(x, n1g, n1b, ln1out);
    // 2. QKV GEMM (q/k per-head, v transposed)
    gemm_kernel<128, 384, 0><<<dim3(Mrows/128, 3), 256, 0, stream>>>(
        ln1out, qkvw_b, qkvb, qbuf, kbuf, vbuf, nullptr);
    // 3. MFMA windowed attention (block = window)
    attn_kernel<<<WTOT, 256, 0, stream>>>(qbuf, kbuf, vbuf, bmt, attno);
    // 4. proj GEMM
    gemm_kernel<128, 128, 1><<<dim3(Mrows/128, 1), 256, 0, stream>>>(
        attno, projw_b, projb, projout, nullptr, nullptr, nullptr);
    // 5. fused window-reverse + unshift + residual + LN2 (disjoint in/out)
    resln_kernel<<<Mrows, 128, 0, stream>>>(x, projout, n2g, n2b, x2, ln2out);
    // 6. FC1 + GELU
    gemm_kernel<128, 512, 2><<<dim3(Mrows/128, 4), 256, 0, stream>>>(
        ln2out, fc1w_b, fc1b, hid, nullptr, nullptr, nullptr);
    // 7. FC2 + residual -> out (fp32)
    gemm_kernel<512, 128, 3><<<dim3(Mrows/128, 1), 256, 0, stream>>>(
        hid, fc2w_b, fc2b, out, nullptr, nullptr, x2);
}